// Round 1
// baseline (131.974 us; speedup 1.0000x reference)
//
#include <hip/hip_runtime.h>
#include <float.h>

#define B_SZ   64
#define T_FR   20
#define K_SEL  5
#define C_CH   3
#define D_SKIM 245760
#define HW224  50176   // 224*224

// ---------------------------------------------------------------------------
// Kernel 1: fea[64][64] = Full_Frame64.reshape(64, 245760) @ W_skim
// Split-K: 480 blocks x (8 tiles of 64 d-steps) = 245760. Each block stages
// At[d][b] (A transposed) and Ws[d][j] in LDS (stride 68 -> 2-way banks, free),
// each thread accumulates a 4b x 4j register tile, then atomicAdd into fea.
// ---------------------------------------------------------------------------
#define K1_BLOCKS 480
#define K1_TILES  8    // 480 * 8 * 64 == 245760

__global__ __launch_bounds__(256) void skim_gemm(
    const float* __restrict__ A, const float* __restrict__ W,
    float* __restrict__ fea) {
  __shared__ float At[64][68];
  __shared__ float Ws[64][68];
  const int t  = threadIdx.x;
  const int jq = (t & 15) << 2;   // j quad base 0..60
  const int bq = (t >> 4) << 2;   // b quad base 0..60
  const int row = t >> 2;         // 0..63 (batch row for A, d-row for W)
  const int q   = t & 3;

  float acc[4][4];
#pragma unroll
  for (int i = 0; i < 4; ++i)
#pragma unroll
    for (int j = 0; j < 4; ++j) acc[i][j] = 0.f;

  const long d_base = (long)blockIdx.x * (K1_TILES * 64);

  for (int tile = 0; tile < K1_TILES; ++tile) {
    const long d0 = d_base + (long)tile * 64;
    __syncthreads();   // protect LDS from previous tile's readers
#pragma unroll
    for (int p = 0; p < 4; ++p) {
      const int off = (q << 2) + (p << 4);   // 0..63, step pattern
      // A[row][d0+off .. +3]  ->  At[off+i][row]
      float4 a4 = *reinterpret_cast<const float4*>(A + (long)row * D_SKIM + d0 + off);
      At[off + 0][row] = a4.x;
      At[off + 1][row] = a4.y;
      At[off + 2][row] = a4.z;
      At[off + 3][row] = a4.w;
      // W[d0+row][off .. +3]  ->  Ws[row][off .. +3]
      float4 w4 = *reinterpret_cast<const float4*>(W + (d0 + row) * 64 + off);
      *reinterpret_cast<float4*>(&Ws[row][off]) = w4;
    }
    __syncthreads();
#pragma unroll 8
    for (int d = 0; d < 64; ++d) {
      float4 av = *reinterpret_cast<const float4*>(&At[d][bq]);
      float4 wv = *reinterpret_cast<const float4*>(&Ws[d][jq]);
      const float a[4] = {av.x, av.y, av.z, av.w};
      const float w[4] = {wv.x, wv.y, wv.z, wv.w};
#pragma unroll
      for (int i = 0; i < 4; ++i)
#pragma unroll
        for (int j = 0; j < 4; ++j)
          acc[i][j] = fmaf(a[i], w[j], acc[i][j]);
    }
  }
#pragma unroll
  for (int i = 0; i < 4; ++i)
#pragma unroll
    for (int j = 0; j < 4; ++j)
      atomicAdd(&fea[(bq + i) * 64 + (jq + j)], acc[i][j]);
}

// ---------------------------------------------------------------------------
// Kernel 2: logits = relu(fea + b_skim) @ W_pol + b_pol ; top-5 indices,
// stable (lowest index on ties, matching jax.lax.top_k), sorted ascending.
// Softmax skipped: strictly monotonic, does not change top-k selection.
// One block (1 wave) per batch row.
// ---------------------------------------------------------------------------
__global__ void policy_topk(const float* __restrict__ fea,
                            const float* __restrict__ b_skim,
                            const float* __restrict__ W_pol,
                            const float* __restrict__ b_pol,
                            int* __restrict__ idx_out) {
  const int b = blockIdx.x;
  const int j = threadIdx.x;   // 64 threads, lanes 0..19 active for logits
  __shared__ float lg_sh[20];
  if (j < 20) {
    float accj = b_pol[j];
    for (int k = 0; k < 64; ++k) {
      float v = fea[b * 64 + k] + b_skim[k];
      v = fmaxf(v, 0.f);
      accj = fmaf(v, W_pol[k * 20 + j], accj);
    }
    lg_sh[j] = accj;
  }
  __syncthreads();
  if (j == 0) {
    float lg[20];
#pragma unroll
    for (int i = 0; i < 20; ++i) lg[i] = lg_sh[i];
    int sel[K_SEL];
#pragma unroll
    for (int s = 0; s < K_SEL; ++s) {
      int bi = 0;
      float bv = lg[0];
      for (int i = 1; i < 20; ++i) {
        if (lg[i] > bv) { bv = lg[i]; bi = i; }   // strict > : lowest idx wins ties
      }
      sel[s] = bi;
      lg[bi] = -FLT_MAX;
    }
    // insertion sort ascending
#pragma unroll
    for (int a = 1; a < K_SEL; ++a) {
      int v = sel[a], c = a;
      while (c > 0 && sel[c - 1] > v) { sel[c] = sel[c - 1]; --c; }
      sel[c] = v;
    }
#pragma unroll
    for (int s = 0; s < K_SEL; ++s) idx_out[b * K_SEL + s] = sel[s];
  }
}

// ---------------------------------------------------------------------------
// Kernel 3: pooled[b][s*3+c] = mean over 224x224 of Full_Frame224[b, idx[b][s], c]
// One block per (b, s, c) triple: 960 blocks x 256 threads, float4 loads.
// ---------------------------------------------------------------------------
__global__ __launch_bounds__(256) void gather_pool(
    const float* __restrict__ F224, const int* __restrict__ idx,
    float* __restrict__ pooled) {
  const int blk = blockIdx.x;        // b*15 + s*3 + c
  const int b = blk / 15;
  const int r = blk % 15;
  const int s = r / 3;
  const int c = r % 3;
  const int fr = idx[b * K_SEL + s];
  const float4* img = reinterpret_cast<const float4*>(
      F224 + (((long)b * T_FR + fr) * C_CH + c) * (long)HW224);
  float sum = 0.f;
  for (int i = threadIdx.x; i < HW224 / 4; i += 256) {
    float4 v = img[i];
    sum += (v.x + v.y) + (v.z + v.w);
  }
#pragma unroll
  for (int off = 32; off > 0; off >>= 1) sum += __shfl_down(sum, off);
  __shared__ float red[4];
  if ((threadIdx.x & 63) == 0) red[threadIdx.x >> 6] = sum;
  __syncthreads();
  if (threadIdx.x == 0)
    pooled[blk] = (red[0] + red[1] + red[2] + red[3]) * (1.0f / HW224);
}

// ---------------------------------------------------------------------------
// Kernel 4: out[64][400] = pooled[64][15] @ W_eval[15][400] + b_eval
// ---------------------------------------------------------------------------
__global__ __launch_bounds__(256) void eval_gemm(
    const float* __restrict__ pooled, const float* __restrict__ W_eval,
    const float* __restrict__ b_eval, float* __restrict__ out) {
  const int g = blockIdx.x * 256 + threadIdx.x;
  if (g >= B_SZ * 400) return;
  const int b = g / 400;
  const int n = g % 400;
  float o = b_eval[n];
#pragma unroll
  for (int k = 0; k < 15; ++k)
    o = fmaf(pooled[b * 15 + k], W_eval[k * 400 + n], o);
  out[g] = o;
}

// ---------------------------------------------------------------------------
extern "C" void kernel_launch(void* const* d_in, const int* in_sizes, int n_in,
                              void* d_out, int out_size, void* d_ws, size_t ws_size,
                              hipStream_t stream) {
  const float* F64    = (const float*)d_in[0];  // [64,20,3,64,64]
  const float* F224   = (const float*)d_in[1];  // [64,20,3,224,224]
  const float* W_skim = (const float*)d_in[2];  // [245760,64]
  const float* b_skim = (const float*)d_in[3];  // [64]
  const float* W_pol  = (const float*)d_in[4];  // [64,20]
  const float* b_pol  = (const float*)d_in[5];  // [20]
  const float* W_eval = (const float*)d_in[6];  // [15,400]
  const float* b_eval = (const float*)d_in[7];  // [400]
  float* out = (float*)d_out;                   // [64,400] fp32

  char* ws = (char*)d_ws;
  float* fea    = (float*)ws;             // 4096 floats  (16384 B)
  int*   idx    = (int*)(ws + 16384);     // 320 ints
  float* pooled = (float*)(ws + 20480);   // 960 floats

  // fea accumulator must start at zero on EVERY call (graph replays reuse ws)
  hipMemsetAsync(fea, 0, 4096 * sizeof(float), stream);

  skim_gemm<<<K1_BLOCKS, 256, 0, stream>>>(F64, W_skim, fea);
  policy_topk<<<B_SZ, 64, 0, stream>>>(fea, b_skim, W_pol, b_pol, idx);
  gather_pool<<<B_SZ * K_SEL * C_CH, 256, 0, stream>>>(F224, idx, pooled);
  eval_gemm<<<(B_SZ * 400 + 255) / 256, 256, 0, stream>>>(pooled, W_eval, b_eval, out);
}